// Round 14
// baseline (164.156 us; speedup 1.0000x reference)
//
#include <hip/hip_runtime.h>
#include <stdint.h>

// SparseAttentionMaskGenerator: per-(b,h) 0.95-quantile threshold mask.
// mask = scores >= x_(K_SEL) per head (0-indexed ascending order statistic);
// bit-exact vs jnp/np linear-interpolated quantile. Output: int32 0/1.
//
// R13 found nt streaming hints = +20us on the fused pass (147us). R14 combines
// the two proven-good pieces: BITMAP stream decoupling (R12, correct but null
// without nt) + NT hints (R13's win):
//   k_pass1 : pure nt-read stream; ballot-pack provisional mask (x>=WEND) into
//             8.4 MB L2-resident bitmap; ballot-popcount below; stage window.
//   k_thresh: exact threshold; inline full-rescan fallback (never taken).
//   k_fixbits: atomicOr window bits with val>=thr (covered); full rebuild (never).
//   k_expand: bitmap -> int32 out, pure nt-write stream (fill shape = 7 TB/s).

#define NUM_HEADS 16
#define PER_HEAD (1u << 22)          // 2048*2048 per head
#define K_SEL 3984588u               // floor(0.95*(N-1)) + 1
#define WSTART 1.6298828125f         // 1 + 1290/2048 (exact float)
#define WEND   1.66015625f           // 1 + 1352/2048 (exact float)
#define WBIN0 1290
#define WBINS 62                     // quantile 1.6449 +- ~0.001; window +-15 bins
#define CAND_CAP 16384               // expected ~13.1K/head (29 sigma margin)
#define WBUF_CAP 384                 // per-block staging; lambda ~102 @128 blk/head
#define FILT_CAP 768                 // target-bin candidates ~210 expected
#define NBINS_FB 2050
#define HEAD_W64 65536ull            // u64 bitmap words per head (4 per 256 elems)
#define UNR 4

typedef int   int4v   __attribute__((ext_vector_type(4)));
typedef float float4v __attribute__((ext_vector_type(4)));

// ws layout (bytes): below u32[16] @0, cnt u32[16] @64, ovf u32[16] @128,
//   cov u32[16] @192, thr f32[16] @256, cval @4096 (1MiB), cpos @+1MiB,
//   bitmap u64[16*65536] @OFF_BMP (8 MiB).
#define OFF_CNT   64
#define OFF_OVF   128
#define OFF_COV   192
#define OFF_THR   256
#define OFF_CVAL  4096
#define OFF_CPOS  (4096 + NUM_HEADS * CAND_CAP * 4)
#define OFF_BMP   (OFF_CPOS + NUM_HEADS * CAND_CAP * 4)
#define ZERO_WORDS 64                // below+cnt+ovf+cov

__global__ void k_zero(uint32_t* __restrict__ ws) {
    if (threadIdx.x < ZERO_WORDS) ws[threadIdx.x] = 0u;
}

__global__ void k_pass1(const float* __restrict__ scores, uint64_t* __restrict__ bmp,
                        uint32_t* __restrict__ below, uint32_t* __restrict__ cnt,
                        uint32_t* __restrict__ ovf, uint32_t* __restrict__ cpos,
                        float* __restrict__ cval) {
    __shared__ uint32_t wpos[WBUF_CAP];
    __shared__ float    wval[WBUF_CAP];
    __shared__ uint32_t wcnt, wbase;
    __shared__ uint32_t wavesum[4];
    const int h = blockIdx.y;
    if (threadIdx.x == 0) wcnt = 0;
    __syncthreads();
    const float4v* p = (const float4v*)(scores + (size_t)h * PER_HEAD);
    uint64_t* wb = bmp + (uint64_t)h * HEAD_W64;
    const uint32_t nvec = PER_HEAD / 4;                 // 1,048,576
    const uint32_t stride = gridDim.x * blockDim.x;     // 32,768 (div by 64)
    const int lane = threadIdx.x & 63, wid = threadIdx.x >> 6;
    uint64_t nb64 = 0;                                  // wave-uniform below count
    uint32_t base = blockIdx.x * blockDim.x + threadIdx.x;   // base & 63 == lane
    for (; base + (UNR - 1) * stride < nvec; base += UNR * stride) {
        float4v v[UNR];
#pragma unroll
        for (int k = 0; k < UNR; ++k)
            v[k] = __builtin_nontemporal_load(&p[base + k * stride]);  // nt read stream
        bool lanehit = false;
#pragma unroll
        for (int k = 0; k < UNR; ++k) {
            const uint32_t gi = base + k * stride;      // gi & 63 == lane
            uint64_t b[4];
#pragma unroll
            for (int j = 0; j < 4; ++j) {
                float x = v[k][j];
                b[j] = __ballot(x >= WEND);             // provisional mask bits
                nb64 += __popcll(__ballot(x < WSTART)); // wave-uniform
                lanehit |= (x >= WSTART && x < WEND);
            }
            if (lane == 0) {                            // 32B per 256 elements
                uint64_t* w = wb + (size_t)(gi >> 6) * 4;
                w[0] = b[0]; w[1] = b[1]; w[2] = b[2]; w[3] = b[3];
            }
        }
        if (__any(lanehit)) {                           // ~3 hits per 1024-elem step
#pragma unroll
            for (int k = 0; k < UNR; ++k) {
#pragma unroll
                for (int j = 0; j < 4; ++j) {
                    float x = v[k][j];
                    if (x >= WSTART && x < WEND) {
                        uint32_t pos = atomicAdd(&wcnt, 1u);
                        if (pos < WBUF_CAP) {
                            wpos[pos] = (base + k * stride) * 4u + j;
                            wval[pos] = x;
                        }
                    }
                }
            }
        }
    }
    // generic tail (not taken for the shipped grid)
    for (; base < nvec; base += stride) {
        float4v v = __builtin_nontemporal_load(&p[base]);
        uint64_t b[4];
        bool lanehit = false;
#pragma unroll
        for (int j = 0; j < 4; ++j) {
            float x = v[j];
            b[j] = __ballot(x >= WEND);
            nb64 += __popcll(__ballot(x < WSTART));
            lanehit |= (x >= WSTART && x < WEND);
        }
        if (lane == 0) {
            uint64_t* w = wb + (size_t)(base >> 6) * 4;
            w[0] = b[0]; w[1] = b[1]; w[2] = b[2]; w[3] = b[3];
        }
        if (__any(lanehit)) {
#pragma unroll
            for (int j = 0; j < 4; ++j) {
                float x = v[j];
                if (x >= WSTART && x < WEND) {
                    uint32_t pos = atomicAdd(&wcnt, 1u);
                    if (pos < WBUF_CAP) { wpos[pos] = base * 4u + j; wval[pos] = x; }
                }
            }
        }
    }
    if (lane == 0) wavesum[wid] = (uint32_t)nb64;       // nb64 identical across wave
    __syncthreads();
    if (threadIdx.x == 0) {
        atomicAdd(&below[h], wavesum[0] + wavesum[1] + wavesum[2] + wavesum[3]);
        uint32_t nc = wcnt;
        if (nc > WBUF_CAP) atomicOr(&ovf[h], 1u);       // robust overflow flag
        wbase = atomicAdd(&cnt[h], min(nc, (uint32_t)WBUF_CAP));
    }
    __syncthreads();
    const uint32_t nc = min(wcnt, (uint32_t)WBUF_CAP);
    const uint32_t bs = wbase;
    for (uint32_t i = threadIdx.x; i < nc; i += blockDim.x) {
        uint32_t pos = bs + i;
        if (pos < CAND_CAP) {
            cpos[h * CAND_CAP + pos] = wpos[i];
            cval[h * CAND_CAP + pos] = wval[i];
        }
    }
}

// Merged threshold kernel: window select, with inline full-rescan fallback
// (never taken for this input; exact coverage test, ~15 sigma margin).
__global__ void k_thresh(const float* __restrict__ scores, const uint32_t* __restrict__ below,
                         const uint32_t* __restrict__ cnt, const uint32_t* __restrict__ ovf,
                         const float* __restrict__ cval, uint32_t* __restrict__ cov,
                         float* __restrict__ thr) {
    const int h = blockIdx.x;
    __shared__ uint32_t fh[NBINS_FB];
    __shared__ float fc[FILT_CAP];
    __shared__ uint32_t lcnt, ok;
    __shared__ int sbin;
    __shared__ uint32_t sres;
    const uint32_t craw = cnt[h];
    const long long r = (long long)K_SEL - (long long)below[h];
    const bool window_ok = !(ovf[h] || craw > CAND_CAP || r < 0 || r >= (long long)craw);

    if (window_ok) {
        for (int i = threadIdx.x; i < WBINS; i += blockDim.x) fh[i] = 0;
        if (threadIdx.x == 0) { lcnt = 0; ok = 1; }
        __syncthreads();
        for (uint32_t i = threadIdx.x; i < craw; i += blockDim.x) {
            float x = cval[h * CAND_CAP + i];
            int b = (int)((__float_as_uint(x) >> 12) & 0x7FFu) - WBIN0;  // in [0,WBINS)
            atomicAdd(&fh[b], 1u);
        }
        __syncthreads();
        if (threadIdx.x == 0) {
            uint32_t cum = 0, res = 0;
            int b = 0;
            for (; b < WBINS; ++b) {
                uint32_t nx = cum + fh[b];
                if ((uint32_t)r < nx) { res = (uint32_t)r - cum; break; }
                cum = nx;
            }
            sbin = b; sres = res;
            if (fh[b] > FILT_CAP) ok = 0;         // paranoid: filter overflow
        }
        __syncthreads();
        if (ok) {
            const int tb = sbin;
            const uint32_t r2 = sres;
            for (uint32_t i = threadIdx.x; i < craw; i += blockDim.x) {
                float x = cval[h * CAND_CAP + i];
                int b = (int)((__float_as_uint(x) >> 12) & 0x7FFu) - WBIN0;
                if (b == tb) { uint32_t pos = atomicAdd(&lcnt, 1u); if (pos < FILT_CAP) fc[pos] = x; }
            }
            __syncthreads();
            const uint32_t m = lcnt;   // == fh[tb] <= FILT_CAP
            // Tie-aware rank selection — order-independent of append order.
            for (uint32_t i = threadIdx.x; i < m; i += blockDim.x) {
                float x = fc[i];
                uint32_t less = 0, eq = 0;
                for (uint32_t j = 0; j < m; ++j) {
                    float y = fc[j];
                    less += (y < x);
                    eq += (y == x);
                }
                if (less <= r2 && r2 < less + eq) thr[h] = x;
            }
            __syncthreads();
            if (threadIdx.x == 0) cov[h] = 1u;
            return;
        }
        __syncthreads();                          // reuse LDS below
    }
    // ---- exact fallback: 2050-bin LDS histogram, two rescans of the head ----
    for (int i = threadIdx.x; i < NBINS_FB; i += blockDim.x) fh[i] = 0;
    if (threadIdx.x == 0) lcnt = 0;
    __syncthreads();
    const float* p = scores + (size_t)h * PER_HEAD;
    for (uint32_t i = threadIdx.x; i < PER_HEAD; i += blockDim.x) {
        float x = p[i];
        int b = (x < 1.0f) ? 0 : ((x >= 2.0f) ? (NBINS_FB - 1)
                                              : 1 + (int)((__float_as_uint(x) >> 12) & 0x7FFu));
        atomicAdd(&fh[b], 1u);
    }
    __syncthreads();
    if (threadIdx.x == 0) {
        uint64_t cum = 0; uint32_t res = 0; int b = 0;
        for (; b < NBINS_FB; ++b) {
            uint64_t nx = cum + fh[b];
            if ((uint64_t)K_SEL < nx) { res = (uint32_t)(K_SEL - cum); break; }
            cum = nx;
        }
        sbin = b; sres = res;
    }
    __syncthreads();
    const int tb = sbin;
    const uint32_t r2 = sres;
    for (uint32_t i = threadIdx.x; i < PER_HEAD; i += blockDim.x) {
        float x = p[i];
        int b = (x < 1.0f) ? 0 : ((x >= 2.0f) ? (NBINS_FB - 1)
                                              : 1 + (int)((__float_as_uint(x) >> 12) & 0x7FFu));
        if (b == tb) { uint32_t pos = atomicAdd(&lcnt, 1u); if (pos < FILT_CAP) fc[pos] = x; }
    }
    __syncthreads();
    const uint32_t m = min(lcnt, (uint32_t)FILT_CAP);
    for (uint32_t i = threadIdx.x; i < m; i += blockDim.x) {
        float x = fc[i];
        uint32_t less = 0, eq = 0;
        for (uint32_t j = 0; j < m; ++j) {
            float y = fc[j];
            less += (y < x);
            eq += (y == x);
        }
        if (less <= r2 && r2 < less + eq) thr[h] = x;
    }
}

// Covered heads: set bits for window elems with val>=thr (provisional bit was
// 0 since x<WEND). Uncovered heads (never): full ballot rebuild with exact thr.
__global__ void k_fixbits(const float* __restrict__ scores, const uint32_t* __restrict__ cnt,
                          const uint32_t* __restrict__ cov, const uint32_t* __restrict__ cpos,
                          const float* __restrict__ cval, const float* __restrict__ thr,
                          uint64_t* __restrict__ bmp) {
    const int h = blockIdx.y;
    const float t = thr[h];
    uint64_t* wb = bmp + (uint64_t)h * HEAD_W64;
    if (cov[h]) {
        const uint32_t n = min(cnt[h], (uint32_t)CAND_CAP);
        for (uint32_t i = blockIdx.x * blockDim.x + threadIdx.x; i < n;
             i += gridDim.x * blockDim.x) {
            uint32_t pos = cpos[h * CAND_CAP + i];
            float val = cval[h * CAND_CAP + i];
            if (val >= t) {
                atomicOr(&wb[(size_t)(pos >> 8) * 4 + (pos & 3)],
                         1ull << ((pos >> 2) & 63));
            }
        }
    } else {
        // exact rebuild (never taken): ballots with the true threshold
        const float4v* p = (const float4v*)(scores + (size_t)h * PER_HEAD);
        const uint32_t nvec = PER_HEAD / 4;
        const uint32_t stride = gridDim.x * blockDim.x;   // div by 64
        const int lane = threadIdx.x & 63;
        for (uint32_t gi = blockIdx.x * blockDim.x + threadIdx.x; gi < nvec; gi += stride) {
            float4v v = p[gi];
            uint64_t b[4];
#pragma unroll
            for (int j = 0; j < 4; ++j) b[j] = __ballot(v[j] >= t);
            if (lane == 0) {
                uint64_t* w = wb + (size_t)(gi >> 6) * 4;
                w[0] = b[0]; w[1] = b[1]; w[2] = b[2]; w[3] = b[3];
            }
        }
    }
}

// Bitmap -> int32 expansion: ~8 MB L2-resident reads, 268 MB pure nt writes.
__global__ void k_expand(const uint64_t* __restrict__ bmp, int* __restrict__ out) {
    const int h = blockIdx.y;
    const int lane = threadIdx.x & 63;
    const uint64_t* wb = bmp + (uint64_t)h * HEAD_W64;
    int4v* o = (int4v*)(out + (size_t)h * PER_HEAD);
    const uint32_t nvec = PER_HEAD / 4;
    const uint32_t stride = gridDim.x * blockDim.x;       // div by 64
    for (uint32_t gi = blockIdx.x * blockDim.x + threadIdx.x; gi < nvec; gi += stride) {
        const uint64_t* w = wb + (size_t)(gi >> 6) * 4;   // wave-uniform addr
        uint64_t w0 = w[0], w1 = w[1], w2 = w[2], w3 = w[3];
        int4v m;
        m.x = (int)((w0 >> lane) & 1ull);
        m.y = (int)((w1 >> lane) & 1ull);
        m.z = (int)((w2 >> lane) & 1ull);
        m.w = (int)((w3 >> lane) & 1ull);
        __builtin_nontemporal_store(m, &o[gi]);           // nt write stream
    }
}

extern "C" void kernel_launch(void* const* d_in, const int* in_sizes, int n_in,
                              void* d_out, int out_size, void* d_ws, size_t ws_size,
                              hipStream_t stream) {
    const float* scores = (const float*)d_in[0];
    int* out = (int*)d_out;
    uint8_t* ws = (uint8_t*)d_ws;

    uint32_t* below = (uint32_t*)ws;
    uint32_t* cnt   = (uint32_t*)(ws + OFF_CNT);
    uint32_t* ovf   = (uint32_t*)(ws + OFF_OVF);
    uint32_t* cov   = (uint32_t*)(ws + OFF_COV);
    float*    thr   = (float*)(ws + OFF_THR);
    float*    cval  = (float*)(ws + OFF_CVAL);
    uint32_t* cpos  = (uint32_t*)(ws + OFF_CPOS);
    uint64_t* bmp   = (uint64_t*)(ws + OFF_BMP);

    dim3 blk(256);
    k_zero<<<1, 64, 0, stream>>>((uint32_t*)ws);
    k_pass1<<<dim3(128, NUM_HEADS), blk, 0, stream>>>(scores, bmp, below, cnt, ovf, cpos, cval);
    k_thresh<<<NUM_HEADS, 256, 0, stream>>>(scores, below, cnt, ovf, cval, cov, thr);
    k_fixbits<<<dim3(64, NUM_HEADS), blk, 0, stream>>>(scores, cnt, cov, cpos, cval, thr, bmp);
    k_expand<<<dim3(256, NUM_HEADS), blk, 0, stream>>>(bmp, out);
}

// Round 15
// 145.180 us; speedup vs baseline: 1.1307x; 1.1307x over previous
//
#include <hip/hip_runtime.h>
#include <stdint.h>

// SparseAttentionMaskGenerator: per-(b,h) 0.95-quantile threshold mask.
// mask = scores >= x_(K_SEL) per head (0-indexed ascending order statistic);
// bit-exact vs jnp/np linear-interpolated quantile. Output: int32 0/1.
//
// R15 ablation: R13's fused single pass (best known, 147us) with nt STORES
// kept and nt LOADS removed. Disambiguates which side of R13's +20us win was
// causal: (a) nt stores preserving input LLC residency -> plain loads win;
// (b) nt loads bypassing a slow LLC-hit path -> this regresses, R13 is final.

#define NUM_HEADS 16
#define PER_HEAD (1u << 22)          // 2048*2048 per head
#define K_SEL 3984588u               // floor(0.95*(N-1)) + 1
#define WSTART 1.6298828125f         // 1 + 1290/2048 (exact float)
#define WEND   1.66015625f           // 1 + 1352/2048 (exact float)
#define WBIN0 1290
#define WBINS 62                     // quantile 1.6449 +- ~0.001; window +-15 bins
#define CAND_CAP 16384               // expected ~13.1K/head (29 sigma margin)
#define WBUF_CAP 384                 // per-block staging; lambda ~102 @128 blk/head
#define FILT_CAP 768                 // target-bin candidates ~210 expected
#define NBINS_FB 2050
#define UNR 4

typedef int   int4v   __attribute__((ext_vector_type(4)));
typedef float float4v __attribute__((ext_vector_type(4)));

// ws layout (bytes): below u32[16] @0, cnt u32[16] @64, ovf u32[16] @128,
//   cov u32[16] @192, thr f32[16] @256, cval f32[16][CAND_CAP] @4096,
//   cpos u32[16][CAND_CAP] @+1MiB.
#define OFF_CNT   64
#define OFF_OVF   128
#define OFF_COV   192
#define OFF_THR   256
#define OFF_CVAL  4096
#define OFF_CPOS  (4096 + NUM_HEADS * CAND_CAP * 4)
#define ZERO_WORDS 64                // below+cnt+ovf+cov

__global__ void k_zero(uint32_t* __restrict__ ws) {
    if (threadIdx.x < ZERO_WORDS) ws[threadIdx.x] = 0u;
}

__global__ void k_pass1(const float* __restrict__ scores, int* __restrict__ out,
                        uint32_t* __restrict__ below, uint32_t* __restrict__ cnt,
                        uint32_t* __restrict__ ovf, uint32_t* __restrict__ cpos,
                        float* __restrict__ cval) {
    __shared__ uint32_t wpos[WBUF_CAP];
    __shared__ float    wval[WBUF_CAP];
    __shared__ uint32_t wcnt, wbase;
    __shared__ uint32_t wavesum[4];
    const int h = blockIdx.y;
    if (threadIdx.x == 0) wcnt = 0;
    __syncthreads();
    const float4v* p = (const float4v*)(scores + (size_t)h * PER_HEAD);
    int4v* o = (int4v*)(out + (size_t)h * PER_HEAD);
    const uint32_t nvec = PER_HEAD / 4;                 // 1,048,576
    const uint32_t stride = gridDim.x * blockDim.x;     // 32,768
    const int lane = threadIdx.x & 63, wid = threadIdx.x >> 6;
    uint64_t nb64 = 0;                                  // wave-uniform below count
    uint32_t base = blockIdx.x * blockDim.x + threadIdx.x;
    // nvec == 32*stride for the shipped grid -> 8 unrolled steps, no tail
    for (; base + (UNR - 1) * stride < nvec; base += UNR * stride) {
        float4v v[UNR];
#pragma unroll
        for (int k = 0; k < UNR; ++k)
            v[k] = p[base + k * stride];         // PLAIN loads (LLC-cached) — the ablation
        bool lanehit = false;
#pragma unroll
        for (int k = 0; k < UNR; ++k) {
            int4v m;
#pragma unroll
            for (int j = 0; j < 4; ++j) {
                float x = v[k][j];
                bool c1 = (x < WSTART), c2 = (x < WEND);
                m[j] = c2 ? 0 : 1;               // provisional: x >= WEND
                nb64 += __popcll(__ballot(c1));  // wave-uniform below count
                lanehit |= (c1 != c2);           // x in [WSTART, WEND)
            }
            __builtin_nontemporal_store(m, &o[base + k * stride]);  // nt write stream
        }
        if (__any(lanehit)) {                    // ~3 hits per 1024-elem step
#pragma unroll
            for (int k = 0; k < UNR; ++k) {
#pragma unroll
                for (int j = 0; j < 4; ++j) {
                    float x = v[k][j];
                    if (x >= WSTART && x < WEND) {
                        uint32_t pos = atomicAdd(&wcnt, 1u);
                        if (pos < WBUF_CAP) {
                            wpos[pos] = (base + k * stride) * 4u + j;
                            wval[pos] = x;
                        }
                    }
                }
            }
        }
    }
    // generic tail (not taken for the shipped grid)
    for (; base < nvec; base += stride) {
        float4v v = p[base];
        int4v m;
#pragma unroll
        for (int j = 0; j < 4; ++j) {
            float x = v[j];
            m[j] = (x >= WEND) ? 1 : 0;
            nb64 += __popcll(__ballot(x < WSTART));
            if (x >= WSTART && x < WEND) {
                uint32_t pos = atomicAdd(&wcnt, 1u);
                if (pos < WBUF_CAP) { wpos[pos] = base * 4u + j; wval[pos] = x; }
            }
        }
        __builtin_nontemporal_store(m, &o[base]);
    }
    if (lane == 0) wavesum[wid] = (uint32_t)nb64;       // nb64 identical across wave
    __syncthreads();
    if (threadIdx.x == 0) {
        atomicAdd(&below[h], wavesum[0] + wavesum[1] + wavesum[2] + wavesum[3]);
        uint32_t nc = wcnt;
        if (nc > WBUF_CAP) atomicOr(&ovf[h], 1u);       // robust overflow flag
        wbase = atomicAdd(&cnt[h], min(nc, (uint32_t)WBUF_CAP));
    }
    __syncthreads();
    const uint32_t nc = min(wcnt, (uint32_t)WBUF_CAP);
    const uint32_t bs = wbase;
    for (uint32_t i = threadIdx.x; i < nc; i += blockDim.x) {
        uint32_t pos = bs + i;
        if (pos < CAND_CAP) {
            cpos[h * CAND_CAP + pos] = wpos[i];
            cval[h * CAND_CAP + pos] = wval[i];
        }
    }
}

// Merged threshold kernel: window select, with inline full-rescan fallback
// (never taken for this input; exact coverage test, ~15 sigma margin).
__global__ void k_thresh(const float* __restrict__ scores, const uint32_t* __restrict__ below,
                         const uint32_t* __restrict__ cnt, const uint32_t* __restrict__ ovf,
                         const float* __restrict__ cval, uint32_t* __restrict__ cov,
                         float* __restrict__ thr) {
    const int h = blockIdx.x;
    __shared__ uint32_t fh[NBINS_FB];
    __shared__ float fc[FILT_CAP];
    __shared__ uint32_t lcnt, ok;
    __shared__ int sbin;
    __shared__ uint32_t sres;
    const uint32_t craw = cnt[h];
    const long long r = (long long)K_SEL - (long long)below[h];
    const bool window_ok = !(ovf[h] || craw > CAND_CAP || r < 0 || r >= (long long)craw);

    if (window_ok) {
        for (int i = threadIdx.x; i < WBINS; i += blockDim.x) fh[i] = 0;
        if (threadIdx.x == 0) { lcnt = 0; ok = 1; }
        __syncthreads();
        for (uint32_t i = threadIdx.x; i < craw; i += blockDim.x) {
            float x = cval[h * CAND_CAP + i];
            int b = (int)((__float_as_uint(x) >> 12) & 0x7FFu) - WBIN0;  // in [0,WBINS)
            atomicAdd(&fh[b], 1u);
        }
        __syncthreads();
        if (threadIdx.x == 0) {
            uint32_t cum = 0, res = 0;
            int b = 0;
            for (; b < WBINS; ++b) {
                uint32_t nx = cum + fh[b];
                if ((uint32_t)r < nx) { res = (uint32_t)r - cum; break; }
                cum = nx;
            }
            sbin = b; sres = res;
            if (fh[b] > FILT_CAP) ok = 0;         // paranoid: filter overflow
        }
        __syncthreads();
        if (ok) {
            const int tb = sbin;
            const uint32_t r2 = sres;
            for (uint32_t i = threadIdx.x; i < craw; i += blockDim.x) {
                float x = cval[h * CAND_CAP + i];
                int b = (int)((__float_as_uint(x) >> 12) & 0x7FFu) - WBIN0;
                if (b == tb) { uint32_t pos = atomicAdd(&lcnt, 1u); if (pos < FILT_CAP) fc[pos] = x; }
            }
            __syncthreads();
            const uint32_t m = lcnt;   // == fh[tb] <= FILT_CAP
            // Tie-aware rank selection — order-independent of append order.
            for (uint32_t i = threadIdx.x; i < m; i += blockDim.x) {
                float x = fc[i];
                uint32_t less = 0, eq = 0;
                for (uint32_t j = 0; j < m; ++j) {
                    float y = fc[j];
                    less += (y < x);
                    eq += (y == x);
                }
                if (less <= r2 && r2 < less + eq) thr[h] = x;
            }
            __syncthreads();
            if (threadIdx.x == 0) cov[h] = 1u;
            return;
        }
        __syncthreads();                          // reuse LDS below
    }
    // ---- exact fallback: 2050-bin LDS histogram, two rescans of the head ----
    for (int i = threadIdx.x; i < NBINS_FB; i += blockDim.x) fh[i] = 0;
    if (threadIdx.x == 0) lcnt = 0;
    __syncthreads();
    const float* p = scores + (size_t)h * PER_HEAD;
    for (uint32_t i = threadIdx.x; i < PER_HEAD; i += blockDim.x) {
        float x = p[i];
        int b = (x < 1.0f) ? 0 : ((x >= 2.0f) ? (NBINS_FB - 1)
                                              : 1 + (int)((__float_as_uint(x) >> 12) & 0x7FFu));
        atomicAdd(&fh[b], 1u);
    }
    __syncthreads();
    if (threadIdx.x == 0) {
        uint64_t cum = 0; uint32_t res = 0; int b = 0;
        for (; b < NBINS_FB; ++b) {
            uint64_t nx = cum + fh[b];
            if ((uint64_t)K_SEL < nx) { res = (uint32_t)(K_SEL - cum); break; }
            cum = nx;
        }
        sbin = b; sres = res;
    }
    __syncthreads();
    const int tb = sbin;
    const uint32_t r2 = sres;
    for (uint32_t i = threadIdx.x; i < PER_HEAD; i += blockDim.x) {
        float x = p[i];
        int b = (x < 1.0f) ? 0 : ((x >= 2.0f) ? (NBINS_FB - 1)
                                              : 1 + (int)((__float_as_uint(x) >> 12) & 0x7FFu));
        if (b == tb) { uint32_t pos = atomicAdd(&lcnt, 1u); if (pos < FILT_CAP) fc[pos] = x; }
    }
    __syncthreads();
    const uint32_t m = min(lcnt, (uint32_t)FILT_CAP);
    for (uint32_t i = threadIdx.x; i < m; i += blockDim.x) {
        float x = fc[i];
        uint32_t less = 0, eq = 0;
        for (uint32_t j = 0; j < m; ++j) {
            float y = fc[j];
            less += (y < x);
            eq += (y == x);
        }
        if (less <= r2 && r2 < less + eq) thr[h] = x;
    }
}

// Merged finish: covered heads -> fix staged window positions only;
// uncovered heads (never, in practice) -> full mask rewrite.
__global__ void k_finish(const float* __restrict__ scores, const uint32_t* __restrict__ cnt,
                         const uint32_t* __restrict__ cov, const uint32_t* __restrict__ cpos,
                         const float* __restrict__ cval, const float* __restrict__ thr,
                         int* __restrict__ out) {
    const int h = blockIdx.y;
    const float t = thr[h];
    if (cov[h]) {
        const uint32_t n = min(cnt[h], (uint32_t)CAND_CAP);
        int* oh = out + (size_t)h * PER_HEAD;
        for (uint32_t i = blockIdx.x * blockDim.x + threadIdx.x; i < n;
             i += gridDim.x * blockDim.x) {
            oh[cpos[h * CAND_CAP + i]] = (cval[h * CAND_CAP + i] >= t) ? 1 : 0;
        }
    } else {
        const float4v* p = (const float4v*)(scores + (size_t)h * PER_HEAD);
        int4v* o = (int4v*)(out + (size_t)h * PER_HEAD);
        const uint32_t nvec = PER_HEAD / 4;
        for (uint32_t i = blockIdx.x * blockDim.x + threadIdx.x; i < nvec;
             i += gridDim.x * blockDim.x) {
            float4v v = p[i];
            int4v m;
            m.x = (v.x >= t) ? 1 : 0;
            m.y = (v.y >= t) ? 1 : 0;
            m.z = (v.z >= t) ? 1 : 0;
            m.w = (v.w >= t) ? 1 : 0;
            o[i] = m;
        }
    }
}

extern "C" void kernel_launch(void* const* d_in, const int* in_sizes, int n_in,
                              void* d_out, int out_size, void* d_ws, size_t ws_size,
                              hipStream_t stream) {
    const float* scores = (const float*)d_in[0];
    int* out = (int*)d_out;
    uint8_t* ws = (uint8_t*)d_ws;

    uint32_t* below = (uint32_t*)ws;
    uint32_t* cnt   = (uint32_t*)(ws + OFF_CNT);
    uint32_t* ovf   = (uint32_t*)(ws + OFF_OVF);
    uint32_t* cov   = (uint32_t*)(ws + OFF_COV);
    float*    thr   = (float*)(ws + OFF_THR);
    float*    cval  = (float*)(ws + OFF_CVAL);
    uint32_t* cpos  = (uint32_t*)(ws + OFF_CPOS);

    dim3 blk(256);
    k_zero<<<1, 64, 0, stream>>>((uint32_t*)ws);
    k_pass1<<<dim3(128, NUM_HEADS), blk, 0, stream>>>(scores, out, below, cnt, ovf, cpos, cval);
    k_thresh<<<NUM_HEADS, 256, 0, stream>>>(scores, below, cnt, ovf, cval, cov, thr);
    k_finish<<<dim3(128, NUM_HEADS), blk, 0, stream>>>(scores, cnt, cov, cpos, cval, thr, out);
}

// Round 16
// 138.263 us; speedup vs baseline: 1.1873x; 1.0500x over previous
//
#include <hip/hip_runtime.h>
#include <stdint.h>

// SparseAttentionMaskGenerator: per-(b,h) 0.95-quantile threshold mask.
// mask = scores >= x_(K_SEL) per head (0-indexed ascending order statistic);
// bit-exact vs jnp/np linear-interpolated quantile. Output: int32 0/1.
//
// R16 (final experiment): champion structure (fused pass, plain loads +
// NT STORES = R15's 145us) with three micro-tweaks:
//   1. 2x oversubscribed grid (4096 blocks) for CU backfill (exact-fit 2048
//      grid has zero load-balance slack).
//   2. per-lane below-count in VGPRs (v_cmp+v_add) instead of per-element
//      ballot+popcll (removes ~48 SALU ops/step from the shared scalar pipe).
//   3. nt stores kept (proven +20us: output stream no longer evicts the
//      half-LLC-resident input).
// Pre-committed: null (>=140us) => declare roofline.

#define NUM_HEADS 16
#define PER_HEAD (1u << 22)          // 2048*2048 per head
#define K_SEL 3984588u               // floor(0.95*(N-1)) + 1
#define WSTART 1.6298828125f         // 1 + 1290/2048 (exact float)
#define WEND   1.66015625f           // 1 + 1352/2048 (exact float)
#define WBIN0 1290
#define WBINS 62                     // quantile 1.6449 +- ~0.001; window +-15 bins
#define CAND_CAP 16384               // expected ~13.1K/head (29 sigma margin)
#define WBUF_CAP 384                 // per-block staging; lambda ~51 @256 blk/head
#define FILT_CAP 768                 // target-bin candidates ~210 expected
#define NBINS_FB 2050
#define UNR 4

typedef int   int4v   __attribute__((ext_vector_type(4)));
typedef float float4v __attribute__((ext_vector_type(4)));

// ws layout (bytes): below u32[16] @0, cnt u32[16] @64, ovf u32[16] @128,
//   cov u32[16] @192, thr f32[16] @256, cval f32[16][CAND_CAP] @4096,
//   cpos u32[16][CAND_CAP] @+1MiB.
#define OFF_CNT   64
#define OFF_OVF   128
#define OFF_COV   192
#define OFF_THR   256
#define OFF_CVAL  4096
#define OFF_CPOS  (4096 + NUM_HEADS * CAND_CAP * 4)
#define ZERO_WORDS 64                // below+cnt+ovf+cov

__global__ void k_zero(uint32_t* __restrict__ ws) {
    if (threadIdx.x < ZERO_WORDS) ws[threadIdx.x] = 0u;
}

__global__ void k_pass1(const float* __restrict__ scores, int* __restrict__ out,
                        uint32_t* __restrict__ below, uint32_t* __restrict__ cnt,
                        uint32_t* __restrict__ ovf, uint32_t* __restrict__ cpos,
                        float* __restrict__ cval) {
    __shared__ uint32_t wpos[WBUF_CAP];
    __shared__ float    wval[WBUF_CAP];
    __shared__ uint32_t wcnt, wbase;
    __shared__ uint32_t wavesum[4];
    const int h = blockIdx.y;
    if (threadIdx.x == 0) wcnt = 0;
    __syncthreads();
    const float4v* p = (const float4v*)(scores + (size_t)h * PER_HEAD);
    int4v* o = (int4v*)(out + (size_t)h * PER_HEAD);
    const uint32_t nvec = PER_HEAD / 4;                 // 1,048,576
    const uint32_t stride = gridDim.x * blockDim.x;     // 65,536 @ 256 blocks/head
    uint32_t nb = 0;                                    // per-lane below count
    uint32_t base = blockIdx.x * blockDim.x + threadIdx.x;
    // nvec == 16*stride for the shipped grid -> 4 unrolled steps, no tail
    for (; base + (UNR - 1) * stride < nvec; base += UNR * stride) {
        float4v v[UNR];
#pragma unroll
        for (int k = 0; k < UNR; ++k)
            v[k] = p[base + k * stride];         // plain loads (LLC-cached)
        bool lanehit = false;
#pragma unroll
        for (int k = 0; k < UNR; ++k) {
            int4v m;
#pragma unroll
            for (int j = 0; j < 4; ++j) {
                float x = v[k][j];
                bool c1 = (x < WSTART), c2 = (x < WEND);
                m[j] = c2 ? 0 : 1;               // provisional: x >= WEND
                nb += c1 ? 1u : 0u;              // per-lane, VALU only
                lanehit |= (c1 != c2);           // x in [WSTART, WEND)
            }
            __builtin_nontemporal_store(m, &o[base + k * stride]);  // nt write stream
        }
        if (__any(lanehit)) {                    // rare clause (~0.3% of elems)
#pragma unroll
            for (int k = 0; k < UNR; ++k) {
#pragma unroll
                for (int j = 0; j < 4; ++j) {
                    float x = v[k][j];
                    if (x >= WSTART && x < WEND) {
                        uint32_t pos = atomicAdd(&wcnt, 1u);
                        if (pos < WBUF_CAP) {
                            wpos[pos] = (base + k * stride) * 4u + j;
                            wval[pos] = x;
                        }
                    }
                }
            }
        }
    }
    // generic tail (not taken for the shipped grid)
    for (; base < nvec; base += stride) {
        float4v v = p[base];
        int4v m;
#pragma unroll
        for (int j = 0; j < 4; ++j) {
            float x = v[j];
            m[j] = (x >= WEND) ? 1 : 0;
            nb += (x < WSTART) ? 1u : 0u;
            if (x >= WSTART && x < WEND) {
                uint32_t pos = atomicAdd(&wcnt, 1u);
                if (pos < WBUF_CAP) { wpos[pos] = base * 4u + j; wval[pos] = x; }
            }
        }
        __builtin_nontemporal_store(m, &o[base]);
    }
    // wave64 reduce + cross-wave LDS reduce of the below-count
#pragma unroll
    for (int off = 32; off > 0; off >>= 1) nb += __shfl_down(nb, off, 64);
    const int lane = threadIdx.x & 63, wid = threadIdx.x >> 6;
    if (lane == 0) wavesum[wid] = nb;
    __syncthreads();
    if (threadIdx.x == 0) {
        atomicAdd(&below[h], wavesum[0] + wavesum[1] + wavesum[2] + wavesum[3]);
        uint32_t nc = wcnt;
        if (nc > WBUF_CAP) atomicOr(&ovf[h], 1u);       // robust overflow flag
        wbase = atomicAdd(&cnt[h], min(nc, (uint32_t)WBUF_CAP));
    }
    __syncthreads();
    const uint32_t nc = min(wcnt, (uint32_t)WBUF_CAP);
    const uint32_t bs = wbase;
    for (uint32_t i = threadIdx.x; i < nc; i += blockDim.x) {
        uint32_t pos = bs + i;
        if (pos < CAND_CAP) {
            cpos[h * CAND_CAP + pos] = wpos[i];
            cval[h * CAND_CAP + pos] = wval[i];
        }
    }
}

// Merged threshold kernel: window select, with inline full-rescan fallback
// (never taken for this input; exact coverage test, ~15 sigma margin).
__global__ void k_thresh(const float* __restrict__ scores, const uint32_t* __restrict__ below,
                         const uint32_t* __restrict__ cnt, const uint32_t* __restrict__ ovf,
                         const float* __restrict__ cval, uint32_t* __restrict__ cov,
                         float* __restrict__ thr) {
    const int h = blockIdx.x;
    __shared__ uint32_t fh[NBINS_FB];
    __shared__ float fc[FILT_CAP];
    __shared__ uint32_t lcnt, ok;
    __shared__ int sbin;
    __shared__ uint32_t sres;
    const uint32_t craw = cnt[h];
    const long long r = (long long)K_SEL - (long long)below[h];
    const bool window_ok = !(ovf[h] || craw > CAND_CAP || r < 0 || r >= (long long)craw);

    if (window_ok) {
        for (int i = threadIdx.x; i < WBINS; i += blockDim.x) fh[i] = 0;
        if (threadIdx.x == 0) { lcnt = 0; ok = 1; }
        __syncthreads();
        for (uint32_t i = threadIdx.x; i < craw; i += blockDim.x) {
            float x = cval[h * CAND_CAP + i];
            int b = (int)((__float_as_uint(x) >> 12) & 0x7FFu) - WBIN0;  // in [0,WBINS)
            atomicAdd(&fh[b], 1u);
        }
        __syncthreads();
        if (threadIdx.x == 0) {
            uint32_t cum = 0, res = 0;
            int b = 0;
            for (; b < WBINS; ++b) {
                uint32_t nx = cum + fh[b];
                if ((uint32_t)r < nx) { res = (uint32_t)r - cum; break; }
                cum = nx;
            }
            sbin = b; sres = res;
            if (fh[b] > FILT_CAP) ok = 0;         // paranoid: filter overflow
        }
        __syncthreads();
        if (ok) {
            const int tb = sbin;
            const uint32_t r2 = sres;
            for (uint32_t i = threadIdx.x; i < craw; i += blockDim.x) {
                float x = cval[h * CAND_CAP + i];
                int b = (int)((__float_as_uint(x) >> 12) & 0x7FFu) - WBIN0;
                if (b == tb) { uint32_t pos = atomicAdd(&lcnt, 1u); if (pos < FILT_CAP) fc[pos] = x; }
            }
            __syncthreads();
            const uint32_t m = lcnt;   // == fh[tb] <= FILT_CAP
            // Tie-aware rank selection — order-independent of append order.
            for (uint32_t i = threadIdx.x; i < m; i += blockDim.x) {
                float x = fc[i];
                uint32_t less = 0, eq = 0;
                for (uint32_t j = 0; j < m; ++j) {
                    float y = fc[j];
                    less += (y < x);
                    eq += (y == x);
                }
                if (less <= r2 && r2 < less + eq) thr[h] = x;
            }
            __syncthreads();
            if (threadIdx.x == 0) cov[h] = 1u;
            return;
        }
        __syncthreads();                          // reuse LDS below
    }
    // ---- exact fallback: 2050-bin LDS histogram, two rescans of the head ----
    for (int i = threadIdx.x; i < NBINS_FB; i += blockDim.x) fh[i] = 0;
    if (threadIdx.x == 0) lcnt = 0;
    __syncthreads();
    const float* p = scores + (size_t)h * PER_HEAD;
    for (uint32_t i = threadIdx.x; i < PER_HEAD; i += blockDim.x) {
        float x = p[i];
        int b = (x < 1.0f) ? 0 : ((x >= 2.0f) ? (NBINS_FB - 1)
                                              : 1 + (int)((__float_as_uint(x) >> 12) & 0x7FFu));
        atomicAdd(&fh[b], 1u);
    }
    __syncthreads();
    if (threadIdx.x == 0) {
        uint64_t cum = 0; uint32_t res = 0; int b = 0;
        for (; b < NBINS_FB; ++b) {
            uint64_t nx = cum + fh[b];
            if ((uint64_t)K_SEL < nx) { res = (uint32_t)(K_SEL - cum); break; }
            cum = nx;
        }
        sbin = b; sres = res;
    }
    __syncthreads();
    const int tb = sbin;
    const uint32_t r2 = sres;
    for (uint32_t i = threadIdx.x; i < PER_HEAD; i += blockDim.x) {
        float x = p[i];
        int b = (x < 1.0f) ? 0 : ((x >= 2.0f) ? (NBINS_FB - 1)
                                              : 1 + (int)((__float_as_uint(x) >> 12) & 0x7FFu));
        if (b == tb) { uint32_t pos = atomicAdd(&lcnt, 1u); if (pos < FILT_CAP) fc[pos] = x; }
    }
    __syncthreads();
    const uint32_t m = min(lcnt, (uint32_t)FILT_CAP);
    for (uint32_t i = threadIdx.x; i < m; i += blockDim.x) {
        float x = fc[i];
        uint32_t less = 0, eq = 0;
        for (uint32_t j = 0; j < m; ++j) {
            float y = fc[j];
            less += (y < x);
            eq += (y == x);
        }
        if (less <= r2 && r2 < less + eq) thr[h] = x;
    }
}

// Merged finish: covered heads -> fix staged window positions only;
// uncovered heads (never, in practice) -> full mask rewrite.
__global__ void k_finish(const float* __restrict__ scores, const uint32_t* __restrict__ cnt,
                         const uint32_t* __restrict__ cov, const uint32_t* __restrict__ cpos,
                         const float* __restrict__ cval, const float* __restrict__ thr,
                         int* __restrict__ out) {
    const int h = blockIdx.y;
    const float t = thr[h];
    if (cov[h]) {
        const uint32_t n = min(cnt[h], (uint32_t)CAND_CAP);
        int* oh = out + (size_t)h * PER_HEAD;
        for (uint32_t i = blockIdx.x * blockDim.x + threadIdx.x; i < n;
             i += gridDim.x * blockDim.x) {
            oh[cpos[h * CAND_CAP + i]] = (cval[h * CAND_CAP + i] >= t) ? 1 : 0;
        }
    } else {
        const float4v* p = (const float4v*)(scores + (size_t)h * PER_HEAD);
        int4v* o = (int4v*)(out + (size_t)h * PER_HEAD);
        const uint32_t nvec = PER_HEAD / 4;
        for (uint32_t i = blockIdx.x * blockDim.x + threadIdx.x; i < nvec;
             i += gridDim.x * blockDim.x) {
            float4v v = p[i];
            int4v m;
            m.x = (v.x >= t) ? 1 : 0;
            m.y = (v.y >= t) ? 1 : 0;
            m.z = (v.z >= t) ? 1 : 0;
            m.w = (v.w >= t) ? 1 : 0;
            o[i] = m;
        }
    }
}

extern "C" void kernel_launch(void* const* d_in, const int* in_sizes, int n_in,
                              void* d_out, int out_size, void* d_ws, size_t ws_size,
                              hipStream_t stream) {
    const float* scores = (const float*)d_in[0];
    int* out = (int*)d_out;
    uint8_t* ws = (uint8_t*)d_ws;

    uint32_t* below = (uint32_t*)ws;
    uint32_t* cnt   = (uint32_t*)(ws + OFF_CNT);
    uint32_t* ovf   = (uint32_t*)(ws + OFF_OVF);
    uint32_t* cov   = (uint32_t*)(ws + OFF_COV);
    float*    thr   = (float*)(ws + OFF_THR);
    float*    cval  = (float*)(ws + OFF_CVAL);
    uint32_t* cpos  = (uint32_t*)(ws + OFF_CPOS);

    dim3 blk(256);
    k_zero<<<1, 64, 0, stream>>>((uint32_t*)ws);
    k_pass1<<<dim3(256, NUM_HEADS), blk, 0, stream>>>(scores, out, below, cnt, ovf, cpos, cval);
    k_thresh<<<NUM_HEADS, 256, 0, stream>>>(scores, below, cnt, ovf, cval, cov, thr);
    k_finish<<<dim3(128, NUM_HEADS), blk, 0, stream>>>(scores, cnt, cov, cpos, cval, thr, out);
}